// Round 5
// baseline (991.084 us; speedup 1.0000x reference)
//
#include <hip/hip_runtime.h>
#include <stdint.h>

typedef unsigned short u16;
typedef __bf16 bf16_t;
typedef bf16_t v8bf __attribute__((ext_vector_type(8)));
typedef u16    v8u  __attribute__((ext_vector_type(8)));
typedef float  v4f  __attribute__((ext_vector_type(4)));

#define NLAYERS 6
#define LN_EPS 1e-5f
#define NROWS 4096      // B*L
#define ND 512
#define NF 2048
#define QKV_LD 1536

// canonical element offsets inside wcan
static constexpr size_t WQKV = 0;                       // 6 * 1536*512
static constexpr size_t WOo  = 4718592;                 // 6 * 512*512
static constexpr size_t W1o  = 6291456;                 // 6 * 2048*512
static constexpr size_t W2o  = 12582912;                // 6 * 512*2048
static constexpr size_t BQKV = 18874368;                // 6 * 1536
static constexpr size_t BOo  = BQKV + 9216;
static constexpr size_t B1o  = BOo + 3072;
static constexpr size_t B2o  = B1o + 12288;
static constexpr size_t L1G  = B2o + 3072, L1B = L1G + 3072;
static constexpr size_t L2G  = L1B + 3072, L2B = L2G + 3072;
static constexpr size_t QMo  = L2B + 3072;

__device__ __forceinline__ float b2f(u16 u){
  union { unsigned int i; float f; } x; x.i = ((unsigned int)u) << 16; return x.f;
}
__device__ __forceinline__ u16 f2b(float f){
  union { float f; unsigned int i; } x; x.f = f;
  unsigned int u = x.i;
  return (u16)((u + 0x7fffu + ((u >> 16) & 1u)) >> 16);
}

__device__ __forceinline__ void gl_lds16(const u16* g, u16* l){
  __builtin_amdgcn_global_load_lds(
      (const __attribute__((address_space(1))) unsigned int*)(g),
      (__attribute__((address_space(3))) unsigned int*)(l), 16, 0, 0);
}

__device__ __forceinline__ void cvt8(const float* __restrict__ src, u16* __restrict__ dst){
  float4 x0 = *(const float4*)(src);
  float4 x1 = *(const float4*)(src + 4);
  v8u o;
  o[0]=f2b(x0.x); o[1]=f2b(x0.y); o[2]=f2b(x0.z); o[3]=f2b(x0.w);
  o[4]=f2b(x1.x); o[5]=f2b(x1.y); o[6]=f2b(x1.z); o[7]=f2b(x1.w);
  *(v8u*)dst = o;
}

// ---------------------------------------------------------------------------
// Setup conversions (fused to minimize launches)
// ---------------------------------------------------------------------------
// query -> xb, key -> kcan (2 x 2097152 elems)
__global__ __launch_bounds__(256) void conv_qk(
    const float* __restrict__ q, const float* __restrict__ k,
    u16* __restrict__ xb, u16* __restrict__ kcan)
{
  const int i = (blockIdx.x * 256 + threadIdx.x) * 8;
  if (i < 2097152) cvt8(q + i, xb + i);
  else             cvt8(k + (i - 2097152), kcan + (i - 2097152));
}

// Wq/Wk/Wv -> per-layer Wqkv slabs
__global__ __launch_bounds__(256) void conv_qkvw(
    const float* __restrict__ wq, const float* __restrict__ wk,
    const float* __restrict__ wv, u16* __restrict__ wcan)
{
  const int i = (blockIdx.x * 256 + threadIdx.x) * 8;
  const float* src; int part, j;
  if (i < 1572864){ part = 0; j = i;           src = wq + j; }
  else if (i < 3145728){ part = 1; j = i - 1572864; src = wk + j; }
  else { part = 2; j = i - 3145728; src = wv + j; }
  const int layer = j >> 18, within = j & 262143;
  cvt8(src, wcan + WQKV + (size_t)layer * 786432 + part * 262144 + within);
}

// WO, W1, W2 contiguous converts
__global__ __launch_bounds__(256) void conv_w3(
    const float* __restrict__ wo, const float* __restrict__ w1,
    const float* __restrict__ w2, u16* __restrict__ wcan)
{
  const int i = (blockIdx.x * 256 + threadIdx.x) * 8;
  if (i < 1572864)      cvt8(wo + i, wcan + WOo + i);
  else if (i < 7864320) cvt8(w1 + (i - 1572864), wcan + W1o + (i - 1572864));
  else                  cvt8(w2 + (i - 7864320), wcan + W2o + (i - 7864320));
}

// all small vectors (biases, LN params, qmask) in one dispatch
__global__ __launch_bounds__(256) void conv_small(
    const float* __restrict__ bqs, const float* __restrict__ bks,
    const float* __restrict__ bvs, const float* __restrict__ bos,
    const float* __restrict__ b1s, const float* __restrict__ b2s,
    const float* __restrict__ g1,  const float* __restrict__ be1,
    const float* __restrict__ g2,  const float* __restrict__ be2,
    const float* __restrict__ qm,  u16* __restrict__ wcan)
{
  const int v = blockIdx.x * 256 + threadIdx.x;
  if (v >= 5504) return;
  const int i = v * 8;
  const float* src; size_t dst;
  if (i < 9216){                       // bq/bk/bv -> interleaved bqkv
    const int part = i / 3072;
    const int j = i - part * 3072;
    src = (part == 0 ? bqs : part == 1 ? bks : bvs) + j;
    dst = BQKV + (size_t)(j >> 9) * 1536 + part * 512 + (j & 511);
  } else if (i < 12288){ const int j = i -  9216; src = bos + j; dst = BOo + j; }
  else if (i < 24576){ const int j = i - 12288; src = b1s + j; dst = B1o + j; }
  else if (i < 27648){ const int j = i - 24576; src = b2s + j; dst = B2o + j; }
  else if (i < 30720){ const int j = i - 27648; src = g1  + j; dst = L1G + j; }
  else if (i < 33792){ const int j = i - 30720; src = be1 + j; dst = L1B + j; }
  else if (i < 36864){ const int j = i - 33792; src = g2  + j; dst = L2G + j; }
  else if (i < 39936){ const int j = i - 36864; src = be2 + j; dst = L2B + j; }
  else               { const int j = i - 39936; src = qm  + j; dst = QMo + j; }
  cvt8(src, wcan + dst);
}

__global__ void compute_len(const float* __restrict__ qm, int* __restrict__ len){
  __shared__ int cnt;
  if (threadIdx.x == 0) cnt = 0;
  __syncthreads();
  int c = 0;
  const int b = blockIdx.x;
  for (int i = threadIdx.x; i < 1024; i += 256)
    if (qm[b * 1024 + i] != 0.f) c++;
  atomicAdd(&cnt, c);
  __syncthreads();
  if (threadIdx.x == 0) len[b] = cnt;
}

// ---------------------------------------------------------------------------
// GEMM: C[M,N] = A[M,K] * W[N,K]^T + bias[N].  m97 structure: 128x128 tile,
// BK=32 staged via global_load_lds (16B), 4 waves, wave tile 64x64 (4x4 acc),
// 16 MFMA : 8 ds_read_b128 per K-step.  Masked m-tiles skipped (lens are
// multiples of 128).  QKV mode: N=1536 composite; A switches at n>=512;
// n>=1024 (V) stores transposed into VT[b][h][d][l].
// ---------------------------------------------------------------------------
template<int RELU, int QKV>
__global__ __launch_bounds__(256) void gemm_k(
    const u16* __restrict__ A0, const u16* __restrict__ A1,
    const u16* __restrict__ W, const u16* __restrict__ bias,
    u16* __restrict__ C, u16* __restrict__ VT,
    const int* __restrict__ len_g, int ldc, int K)
{
  __shared__ __align__(16) u16 As[128 * 32];
  __shared__ __align__(16) u16 Bs[128 * 32];

  const int t    = threadIdx.x;
  const int lane = t & 63, wave = t >> 6;
  const int ln   = lane & 15, quad = lane >> 4;
  const int n0 = blockIdx.x * 128;
  const int m0 = blockIdx.y * 128;
  if ((m0 & 1023) >= len_g[m0 >> 10]) return;   // whole tile masked

  const u16* A = (QKV && n0 >= 512) ? A1 : A0;
  const int wm = wave & 1, wn = wave >> 1;

  v4f acc[4][4];
  #pragma unroll
  for (int i = 0; i < 4; ++i)
    #pragma unroll
    for (int j = 0; j < 4; ++j) acc[i][j] = (v4f){0.f,0.f,0.f,0.f};

  const int u0 = t, u1 = t + 256;
  const u16* aS0 = A + (size_t)(m0 + (u0 >> 2)) * K + (u0 & 3) * 8;
  const u16* aS1 = A + (size_t)(m0 + (u1 >> 2)) * K + (u1 & 3) * 8;
  const u16* bS0 = W + (size_t)(n0 + (u0 >> 2)) * K + (u0 & 3) * 8;
  const u16* bS1 = W + (size_t)(n0 + (u1 >> 2)) * K + (u1 & 3) * 8;

  for (int k0 = 0; k0 < K; k0 += 32){
    gl_lds16(aS0 + k0, &As[u0 * 8]);
    gl_lds16(aS1 + k0, &As[u1 * 8]);
    gl_lds16(bS0 + k0, &Bs[u0 * 8]);
    gl_lds16(bS1 + k0, &Bs[u1 * 8]);
    __syncthreads();

    v8bf a[4], bf[4];
    #pragma unroll
    for (int i = 0; i < 4; ++i)
      a[i] = *(const v8bf*)&As[(wm * 64 + i * 16 + ln) * 32 + quad * 8];
    #pragma unroll
    for (int j = 0; j < 4; ++j)
      bf[j] = *(const v8bf*)&Bs[(wn * 64 + j * 16 + ln) * 32 + quad * 8];
    #pragma unroll
    for (int i = 0; i < 4; ++i)
      #pragma unroll
      for (int j = 0; j < 4; ++j)
        acc[i][j] = __builtin_amdgcn_mfma_f32_16x16x32_bf16(a[i], bf[j], acc[i][j], 0, 0, 0);
    __syncthreads();
  }

  #pragma unroll
  for (int j = 0; j < 4; ++j){
    const int col = n0 + wn * 64 + j * 16 + ln;
    const float bs = b2f(bias[col]);
    #pragma unroll
    for (int i = 0; i < 4; ++i){
      #pragma unroll
      for (int r = 0; r < 4; ++r){
        const int row = m0 + wm * 64 + i * 16 + quad * 4 + r;
        float v = acc[i][j][r] + bs;
        if (RELU) v = fmaxf(v, 0.f);
        if (QKV && col >= 1024){
          const int e = col - 1024;
          VT[(((size_t)(row >> 10) * 8 + (e >> 6)) * 64 + (e & 63)) * 1024 + (row & 1023)] = f2b(v);
        } else {
          C[(size_t)row * ldc + col] = f2b(v);
        }
      }
    }
  }
}

// ---------------------------------------------------------------------------
// Flash attention: one block per (b,h,64 q-rows), 4 waves x 16 q-rows.
// K/V j-tiles (64x64) staged cooperatively in padded LDS (pitch 72),
// shared by all 4 waves, next tile prefetched into registers.
// ---------------------------------------------------------------------------
__global__ __launch_bounds__(256) void attn_kernel(
    const u16* __restrict__ qkv, const u16* __restrict__ VT,
    const int* __restrict__ len_g, u16* __restrict__ O)
{
  __shared__ __align__(16) u16 Ks[64 * 72];
  __shared__ __align__(16) u16 Vs[64 * 72];
  __shared__ __align__(16) u16 Pl[4][16 * 72];

  const int t    = threadIdx.x;
  const int lane = t & 63, wave = t >> 6;
  const int ln   = lane & 15, quad = lane >> 4;
  const int bh = blockIdx.x >> 4;
  const int qc = blockIdx.x & 15;
  const int h = bh & 7, b = bh >> 3;
  const int len = len_g[b];
  if (qc * 64 >= len) return;
  const int q0 = qc * 64 + wave * 16;

  const u16* Qb = qkv + ((size_t)b * 1024 + q0 + ln) * QKV_LD + h * 64;
  const v8bf aq0 = *(const v8bf*)(Qb + quad * 8);
  const v8bf aq1 = *(const v8bf*)(Qb + 32 + quad * 8);

  const u16* Kbase = qkv + (size_t)b * 1024 * QKV_LD + 512 + h * 64;
  const u16* Vbase = VT + (size_t)bh * 64 * 1024;

  const int r0 = t >> 3,         c0 = (t & 7) * 8;
  const int r1 = (t + 256) >> 3, c1 = c0;
  const u16* Kst0 = Kbase + (size_t)r0 * QKV_LD + c0;
  const u16* Kst1 = Kbase + (size_t)r1 * QKV_LD + c1;
  const u16* Vst0 = Vbase + (size_t)r0 * 1024 + c0;
  const u16* Vst1 = Vbase + (size_t)r1 * 1024 + c1;
  u16* KsD0 = &Ks[r0 * 72 + c0]; u16* KsD1 = &Ks[r1 * 72 + c1];
  u16* VsD0 = &Vs[r0 * 72 + c0]; u16* VsD1 = &Vs[r1 * 72 + c1];

  float m_i[4], l_i[4];
  #pragma unroll
  for (int r = 0; r < 4; ++r){ m_i[r] = -1e30f; l_i[r] = 0.f; }
  v4f o_acc[4];
  #pragma unroll
  for (int c = 0; c < 4; ++c) o_acc[c] = (v4f){0.f,0.f,0.f,0.f};

  u16* P = Pl[wave];

  v8u ck0 = *(const v8u*)Kst0;
  v8u ck1 = *(const v8u*)Kst1;
  v8u cv0 = *(const v8u*)Vst0;
  v8u cv1 = *(const v8u*)Vst1;

  for (int j0 = 0; j0 < len; j0 += 64){
    __syncthreads();
    *(v8u*)KsD0 = ck0; *(v8u*)KsD1 = ck1;
    *(v8u*)VsD0 = cv0; *(v8u*)VsD1 = cv1;
    __syncthreads();

    const int jn = j0 + 64;
    if (jn < len){
      ck0 = *(const v8u*)(Kst0 + (size_t)jn * QKV_LD);
      ck1 = *(const v8u*)(Kst1 + (size_t)jn * QKV_LD);
      cv0 = *(const v8u*)(Vst0 + jn);
      cv1 = *(const v8u*)(Vst1 + jn);
    }

    const bool tail = (len - j0) < 64;

    v4f s[4];
    #pragma unroll
    for (int st = 0; st < 4; ++st){
      const u16* kr = &Ks[(st * 16 + ln) * 72];
      v4f ss = {0.f,0.f,0.f,0.f};
      ss = __builtin_amdgcn_mfma_f32_16x16x32_bf16(aq0, *(const v8bf*)(kr + quad * 8),      ss, 0,0,0);
      ss = __builtin_amdgcn_mfma_f32_16x16x32_bf16(aq1, *(const v8bf*)(kr + 32 + quad * 8), ss, 0,0,0);
      s[st] = ss;
    }

    float p[4][4], mt[4];
    #pragma unroll
    for (int r = 0; r < 4; ++r) mt[r] = -1e30f;
    #pragma unroll
    for (int st = 0; st < 4; ++st){
      const bool dead = tail && (j0 + st * 16 + ln) >= len;
      #pragma unroll
      for (int r = 0; r < 4; ++r){
        float sc = dead ? -1e30f : s[st][r] * 0.125f;
        p[st][r] = sc;
        mt[r] = fmaxf(mt[r], sc);
      }
    }
    #pragma unroll
    for (int off = 1; off < 16; off <<= 1)
      #pragma unroll
      for (int r = 0; r < 4; ++r) mt[r] = fmaxf(mt[r], __shfl_xor(mt[r], off));

    float alpha[4], ts[4];
    #pragma unroll
    for (int r = 0; r < 4; ++r){
      const float mn = fmaxf(m_i[r], mt[r]);
      alpha[r] = __expf(m_i[r] - mn);
      m_i[r] = mn;
    }
    #pragma unroll
    for (int st = 0; st < 4; ++st)
      #pragma unroll
      for (int r = 0; r < 4; ++r) p[st][r] = __expf(p[st][r] - m_i[r]);
    #pragma unroll
    for (int r = 0; r < 4; ++r) ts[r] = (p[0][r] + p[1][r]) + (p[2][r] + p[3][r]);
    #pragma unroll
    for (int off = 1; off < 16; off <<= 1)
      #pragma unroll
      for (int r = 0; r < 4; ++r) ts[r] += __shfl_xor(ts[r], off);
    #pragma unroll
    for (int r = 0; r < 4; ++r) l_i[r] = l_i[r] * alpha[r] + ts[r];
    #pragma unroll
    for (int c = 0; c < 4; ++c)
      #pragma unroll
      for (int r = 0; r < 4; ++r) o_acc[c][r] *= alpha[r];

    #pragma unroll
    for (int st = 0; st < 4; ++st)
      #pragma unroll
      for (int r = 0; r < 4; ++r)
        P[(quad * 4 + r) * 72 + st * 16 + ln] = f2b(p[st][r]);
    const v8bf ap0 = *(const v8bf*)&P[ln * 72 + quad * 8];
    const v8bf ap1 = *(const v8bf*)&P[ln * 72 + 32 + quad * 8];

    #pragma unroll
    for (int c = 0; c < 4; ++c){
      const u16* vr = &Vs[(c * 16 + ln) * 72];
      o_acc[c] = __builtin_amdgcn_mfma_f32_16x16x32_bf16(ap0, *(const v8bf*)(vr + quad * 8),      o_acc[c], 0,0,0);
      o_acc[c] = __builtin_amdgcn_mfma_f32_16x16x32_bf16(ap1, *(const v8bf*)(vr + 32 + quad * 8), o_acc[c], 0,0,0);
    }
  }

  u16* Ob = O + ((size_t)b * 1024 + q0) * 512 + h * 64;
  #pragma unroll
  for (int c = 0; c < 4; ++c)
    #pragma unroll
    for (int r = 0; r < 4; ++r)
      Ob[(size_t)(quad * 4 + r) * 512 + c * 16 + ln] = f2b(o_acc[c][r] / l_i[r]);
}

// ---------------------------------------------------------------------------
// Fused residual + query-mask + LayerNorm: X = LN(Y*qm + X) * g + b
// OUT=1: also the final layer -> write f32 to fout instead of xb.
// ---------------------------------------------------------------------------
template<int OUT>
__global__ __launch_bounds__(256) void ln_res(
    const u16* __restrict__ Y, const u16* __restrict__ qm,
    const u16* __restrict__ g, const u16* __restrict__ beta,
    u16* __restrict__ X, float* __restrict__ fout)
{
  const int lane = threadIdx.x & 63;
  const int wave = threadIdx.x >> 6;
  const int row  = blockIdx.x * 4 + wave;

  const float qv = b2f(qm[row]);
  const u16* y = Y + (size_t)row * ND;
  u16*       x = X + (size_t)row * ND;

  v8u yv = *(const v8u*)(y + lane * 8);
  v8u xv = *(const v8u*)(x + lane * 8);
  float tt[8]; float s = 0.f, s2 = 0.f;
  #pragma unroll
  for (int i = 0; i < 8; ++i){
    tt[i] = b2f(yv[i]) * qv + b2f(xv[i]);
    s  += tt[i];
    s2 += tt[i] * tt[i];
  }
  #pragma unroll
  for (int off = 1; off < 64; off <<= 1){
    s  += __shfl_xor(s,  off);
    s2 += __shfl_xor(s2, off);
  }
  const float mean = s * (1.f / ND);
  const float var  = fmaxf(s2 * (1.f / ND) - mean * mean, 0.f);
  const float inv  = rsqrtf(var + LN_EPS);

  v8u gv = *(const v8u*)(g    + lane * 8);
  v8u bv = *(const v8u*)(beta + lane * 8);
  float ov[8];
  #pragma unroll
  for (int i = 0; i < 8; ++i)
    ov[i] = (tt[i] - mean) * inv * b2f(gv[i]) + b2f(bv[i]);

  if (OUT){
    float4 o0, o1;
    o0.x=ov[0]; o0.y=ov[1]; o0.z=ov[2]; o0.w=ov[3];
    o1.x=ov[4]; o1.y=ov[5]; o1.z=ov[6]; o1.w=ov[7];
    float* fo = fout + (size_t)row * ND + lane * 8;
    *(float4*)fo = o0;
    *(float4*)(fo + 4) = o1;
  } else {
    v8u o;
    #pragma unroll
    for (int i = 0; i < 8; ++i) o[i] = f2b(ov[i]);
    *(v8u*)(x + lane * 8) = o;
  }
}

// ---------------------------------------------------------------------------
extern "C" void kernel_launch(void* const* d_in, const int* in_sizes, int n_in,
                              void* d_out, int out_size, void* d_ws, size_t ws_size,
                              hipStream_t stream)
{
  char* ws = (char*)d_ws;
  const size_t MiB = 1u << 20;
  u16* qkv = (u16*)(ws);               // 12 MiB
  u16* VT  = (u16*)(ws + 12 * MiB);    // 4 MiB
  u16* hb  = (u16*)(ws);               // FFN hidden reuses [0,16M)
  u16* tb1 = (u16*)(ws);
  u16* xb   = (u16*)(ws + 16 * MiB);
  u16* kcan = (u16*)(ws + 20 * MiB);
  u16* ob   = (u16*)(ws + 24 * MiB);
  u16* tb2  = ob;
  u16* wcan = (u16*)(ws + 28 * MiB);
  int* len  = (int*)(ws + 65 * MiB);

  const float* f_qm = (const float*)d_in[2];

  conv_qk<<<2048, 256, 0, stream>>>((const float*)d_in[0], (const float*)d_in[1], xb, kcan);
  conv_qkvw<<<2304, 256, 0, stream>>>((const float*)d_in[4], (const float*)d_in[6],
                                      (const float*)d_in[8], wcan);
  conv_w3<<<6912, 256, 0, stream>>>((const float*)d_in[10], (const float*)d_in[12],
                                    (const float*)d_in[14], wcan);
  conv_small<<<22, 256, 0, stream>>>(
      (const float*)d_in[5],  (const float*)d_in[7],  (const float*)d_in[9],
      (const float*)d_in[11], (const float*)d_in[13], (const float*)d_in[15],
      (const float*)d_in[16], (const float*)d_in[17],
      (const float*)d_in[18], (const float*)d_in[19], f_qm, wcan);
  compute_len<<<4, 256, 0, stream>>>(f_qm, len);

  for (int i = 0; i < NLAYERS; ++i){
    const u16* Wqkv_i = wcan + WQKV + (size_t)i * 786432;
    const u16* bqkv_i = wcan + BQKV + (size_t)i * 1536;
    const u16* Wo_i = wcan + WOo + (size_t)i * 262144;
    const u16* W1_i = wcan + W1o + (size_t)i * 1048576;
    const u16* W2_i = wcan + W2o + (size_t)i * 1048576;

    gemm_k<0,1><<<dim3(12, 32), 256, 0, stream>>>(
        xb, kcan, Wqkv_i, bqkv_i, qkv, VT, len, QKV_LD, ND);

    attn_kernel<<<512, 256, 0, stream>>>(qkv, VT, len, ob);

    gemm_k<0,0><<<dim3(4, 32), 256, 0, stream>>>(
        ob, ob, Wo_i, wcan + BOo + (size_t)i * ND, tb1, nullptr, len, ND, ND);
    ln_res<0><<<NROWS / 4, 256, 0, stream>>>(tb1, wcan + QMo,
        wcan + L1G + (size_t)i * ND, wcan + L1B + (size_t)i * ND, xb, nullptr);

    gemm_k<1,0><<<dim3(16, 32), 256, 0, stream>>>(
        xb, xb, W1_i, wcan + B1o + (size_t)i * NF, hb, nullptr, len, NF, ND);
    gemm_k<0,0><<<dim3(4, 32), 256, 0, stream>>>(
        hb, hb, W2_i, wcan + B2o + (size_t)i * ND, tb2, nullptr, len, ND, NF);

    if (i < NLAYERS - 1)
      ln_res<0><<<NROWS / 4, 256, 0, stream>>>(tb2, wcan + QMo,
          wcan + L2G + (size_t)i * ND, wcan + L2B + (size_t)i * ND, xb, nullptr);
    else
      ln_res<1><<<NROWS / 4, 256, 0, stream>>>(tb2, wcan + QMo,
          wcan + L2G + (size_t)i * ND, wcan + L2B + (size_t)i * ND, xb, (float*)d_out);
  }
}

// Round 6
// 817.490 us; speedup vs baseline: 1.2123x; 1.2123x over previous
//
#include <hip/hip_runtime.h>
#include <stdint.h>

typedef unsigned short u16;
typedef __bf16 bf16_t;
typedef bf16_t v8bf __attribute__((ext_vector_type(8)));
typedef u16    v8u  __attribute__((ext_vector_type(8)));
typedef float  v4f  __attribute__((ext_vector_type(4)));

#define NLAYERS 6
#define LN_EPS 1e-5f
#define NROWS 4096      // B*L
#define ND 512
#define NF 2048
#define QKV_LD 1536

// canonical element offsets inside wcan
static constexpr size_t WQKV = 0;                       // 6 * 1536*512
static constexpr size_t WOo  = 4718592;                 // 6 * 512*512
static constexpr size_t W1o  = 6291456;                 // 6 * 2048*512
static constexpr size_t W2o  = 12582912;                // 6 * 512*2048
static constexpr size_t BQKV = 18874368;                // 6 * 1536
static constexpr size_t BOo  = BQKV + 9216;
static constexpr size_t B1o  = BOo + 3072;
static constexpr size_t B2o  = B1o + 12288;
static constexpr size_t L1G  = B2o + 3072, L1B = L1G + 3072;
static constexpr size_t L2G  = L1B + 3072, L2B = L2G + 3072;
static constexpr size_t QMo  = L2B + 3072;

__device__ __forceinline__ float b2f(u16 u){
  union { unsigned int i; float f; } x; x.i = ((unsigned int)u) << 16; return x.f;
}
__device__ __forceinline__ u16 f2b(float f){
  union { float f; unsigned int i; } x; x.f = f;
  unsigned int u = x.i;
  return (u16)((u + 0x7fffu + ((u >> 16) & 1u)) >> 16);
}

__device__ __forceinline__ void gl_lds16(const u16* g, u16* l){
  __builtin_amdgcn_global_load_lds(
      (const __attribute__((address_space(1))) unsigned int*)(g),
      (__attribute__((address_space(3))) unsigned int*)(l), 16, 0, 0);
}

__device__ __forceinline__ void cvt8(const float* __restrict__ src, u16* __restrict__ dst){
  float4 x0 = *(const float4*)(src);
  float4 x1 = *(const float4*)(src + 4);
  v8u o;
  o[0]=f2b(x0.x); o[1]=f2b(x0.y); o[2]=f2b(x0.z); o[3]=f2b(x0.w);
  o[4]=f2b(x1.x); o[5]=f2b(x1.y); o[6]=f2b(x1.z); o[7]=f2b(x1.w);
  *(v8u*)dst = o;
}

// ---------------------------------------------------------------------------
// Setup conversions (fused)
// ---------------------------------------------------------------------------
__global__ __launch_bounds__(256) void conv_qk(
    const float* __restrict__ q, const float* __restrict__ k,
    u16* __restrict__ xb, u16* __restrict__ kcan)
{
  const int i = (blockIdx.x * 256 + threadIdx.x) * 8;
  if (i < 2097152) cvt8(q + i, xb + i);
  else             cvt8(k + (i - 2097152), kcan + (i - 2097152));
}

__global__ __launch_bounds__(256) void conv_qkvw(
    const float* __restrict__ wq, const float* __restrict__ wk,
    const float* __restrict__ wv, u16* __restrict__ wcan)
{
  const int i = (blockIdx.x * 256 + threadIdx.x) * 8;
  const float* src; int part, j;
  if (i < 1572864){ part = 0; j = i;           src = wq + j; }
  else if (i < 3145728){ part = 1; j = i - 1572864; src = wk + j; }
  else { part = 2; j = i - 3145728; src = wv + j; }
  const int layer = j >> 18, within = j & 262143;
  cvt8(src, wcan + WQKV + (size_t)layer * 786432 + part * 262144 + within);
}

__global__ __launch_bounds__(256) void conv_w3(
    const float* __restrict__ wo, const float* __restrict__ w1,
    const float* __restrict__ w2, u16* __restrict__ wcan)
{
  const int i = (blockIdx.x * 256 + threadIdx.x) * 8;
  if (i < 1572864)      cvt8(wo + i, wcan + WOo + i);
  else if (i < 7864320) cvt8(w1 + (i - 1572864), wcan + W1o + (i - 1572864));
  else                  cvt8(w2 + (i - 7864320), wcan + W2o + (i - 7864320));
}

__global__ __launch_bounds__(256) void conv_small(
    const float* __restrict__ bqs, const float* __restrict__ bks,
    const float* __restrict__ bvs, const float* __restrict__ bos,
    const float* __restrict__ b1s, const float* __restrict__ b2s,
    const float* __restrict__ g1,  const float* __restrict__ be1,
    const float* __restrict__ g2,  const float* __restrict__ be2,
    const float* __restrict__ qm,  u16* __restrict__ wcan)
{
  const int v = blockIdx.x * 256 + threadIdx.x;
  if (v >= 5504) return;
  const int i = v * 8;
  const float* src; size_t dst;
  if (i < 9216){
    const int part = i / 3072;
    const int j = i - part * 3072;
    src = (part == 0 ? bqs : part == 1 ? bks : bvs) + j;
    dst = BQKV + (size_t)(j >> 9) * 1536 + part * 512 + (j & 511);
  } else if (i < 12288){ const int j = i -  9216; src = bos + j; dst = BOo + j; }
  else if (i < 24576){ const int j = i - 12288; src = b1s + j; dst = B1o + j; }
  else if (i < 27648){ const int j = i - 24576; src = b2s + j; dst = B2o + j; }
  else if (i < 30720){ const int j = i - 27648; src = g1  + j; dst = L1G + j; }
  else if (i < 33792){ const int j = i - 30720; src = be1 + j; dst = L1B + j; }
  else if (i < 36864){ const int j = i - 33792; src = g2  + j; dst = L2G + j; }
  else if (i < 39936){ const int j = i - 36864; src = be2 + j; dst = L2B + j; }
  else               { const int j = i - 39936; src = qm  + j; dst = QMo + j; }
  cvt8(src, wcan + dst);
}

__global__ void compute_len(const float* __restrict__ qm, int* __restrict__ len){
  __shared__ int cnt;
  if (threadIdx.x == 0) cnt = 0;
  __syncthreads();
  int c = 0;
  const int b = blockIdx.x;
  for (int i = threadIdx.x; i < 1024; i += 256)
    if (qm[b * 1024 + i] != 0.f) c++;
  atomicAdd(&cnt, c);
  __syncthreads();
  if (threadIdx.x == 0) len[b] = cnt;
}

// ---------------------------------------------------------------------------
// GEMM: C[M,N] = A[M,K] * W[N,K]^T + bias[N].  MTxNT tile, BK=32 staged via
// global_load_lds (16B), 4 waves, wave tile (MT/2)x(NT/2), 16x16x32 MFMA.
// LDS bank-conflict fix: global-source XOR swizzle (slot s of row r holds
// k-chunk ((s - (r>>1)) & 3)); reads use sw=(quad+(ln>>1))&3 -> 2 lanes/bank.
// Masked m-tiles skipped. QKV mode: N=1536 composite; A switches at n>=512;
// n>=1024 (V) stores transposed into VT[b][h][d][l].
// ---------------------------------------------------------------------------
template<int MT, int NT, int RELU, int QKV>
__global__ __launch_bounds__(256) void gemm_k(
    const u16* __restrict__ A0, const u16* __restrict__ A1,
    const u16* __restrict__ W, const u16* __restrict__ bias,
    u16* __restrict__ C, u16* __restrict__ VT,
    const int* __restrict__ len_g, int ldc, int K)
{
  constexpr int WM = MT / 2, WN = NT / 2;
  constexpr int NI = WM / 16, NJ = WN / 16;
  constexpr int RA = MT / 64, RB = NT / 64;
  __shared__ __align__(16) u16 As[MT * 32];
  __shared__ __align__(16) u16 Bs[NT * 32];

  const int t    = threadIdx.x;
  const int lane = t & 63, wave = t >> 6;
  const int ln   = lane & 15, quad = lane >> 4;
  const int n0 = blockIdx.x * NT;
  const int m0 = blockIdx.y * MT;
  if ((m0 & 1023) >= len_g[m0 >> 10]) return;   // whole tile masked

  const u16* A = (QKV && n0 >= 512) ? A1 : A0;
  const int wm = wave & 1, wn = wave >> 1;
  const int sw = (quad + (ln >> 1)) & 3;        // swizzled read slot

  v4f acc[NI][NJ];
  #pragma unroll
  for (int i = 0; i < NI; ++i)
    #pragma unroll
    for (int j = 0; j < NJ; ++j) acc[i][j] = (v4f){0.f,0.f,0.f,0.f};

  const u16* aS[RA]; const u16* bS[RB];
  #pragma unroll
  for (int ra = 0; ra < RA; ++ra){
    const int u = t + ra * 256;
    const int c = ((u & 3) - (u >> 3)) & 3;     // swizzled source chunk
    aS[ra] = A + (size_t)(m0 + (u >> 2)) * K + c * 8;
  }
  #pragma unroll
  for (int rb = 0; rb < RB; ++rb){
    const int u = t + rb * 256;
    const int c = ((u & 3) - (u >> 3)) & 3;
    bS[rb] = W + (size_t)(n0 + (u >> 2)) * K + c * 8;
  }

  for (int k0 = 0; k0 < K; k0 += 32){
    #pragma unroll
    for (int ra = 0; ra < RA; ++ra) gl_lds16(aS[ra] + k0, &As[(t + ra*256) * 8]);
    #pragma unroll
    for (int rb = 0; rb < RB; ++rb) gl_lds16(bS[rb] + k0, &Bs[(t + rb*256) * 8]);
    __syncthreads();

    v8bf a[NI], bf[NJ];
    #pragma unroll
    for (int i = 0; i < NI; ++i)
      a[i] = *(const v8bf*)&As[(wm * WM + i * 16 + ln) * 32 + sw * 8];
    #pragma unroll
    for (int j = 0; j < NJ; ++j)
      bf[j] = *(const v8bf*)&Bs[(wn * WN + j * 16 + ln) * 32 + sw * 8];
    #pragma unroll
    for (int i = 0; i < NI; ++i)
      #pragma unroll
      for (int j = 0; j < NJ; ++j)
        acc[i][j] = __builtin_amdgcn_mfma_f32_16x16x32_bf16(a[i], bf[j], acc[i][j], 0, 0, 0);
    __syncthreads();
  }

  #pragma unroll
  for (int j = 0; j < NJ; ++j){
    const int col = n0 + wn * WN + j * 16 + ln;
    const float bs = b2f(bias[col]);
    #pragma unroll
    for (int i = 0; i < NI; ++i){
      #pragma unroll
      for (int r = 0; r < 4; ++r){
        const int row = m0 + wm * WM + i * 16 + quad * 4 + r;
        float v = acc[i][j][r] + bs;
        if (RELU) v = fmaxf(v, 0.f);
        if (QKV && col >= 1024){
          const int e = col - 1024;
          VT[(((size_t)(row >> 10) * 8 + (e >> 6)) * 64 + (e & 63)) * 1024 + (row & 1023)] = f2b(v);
        } else {
          C[(size_t)row * ldc + col] = f2b(v);
        }
      }
    }
  }
}

// ---------------------------------------------------------------------------
// Flash attention: one block per (b,h,64 q-rows), 4 waves x 16 q-rows.
// K/V j-tiles (64x64) staged cooperatively in padded LDS (pitch 72),
// shared by all 4 waves, next tile prefetched into registers.
// ---------------------------------------------------------------------------
__global__ __launch_bounds__(256) void attn_kernel(
    const u16* __restrict__ qkv, const u16* __restrict__ VT,
    const int* __restrict__ len_g, u16* __restrict__ O)
{
  __shared__ __align__(16) u16 Ks[64 * 72];
  __shared__ __align__(16) u16 Vs[64 * 72];
  __shared__ __align__(16) u16 Pl[4][16 * 72];

  const int t    = threadIdx.x;
  const int lane = t & 63, wave = t >> 6;
  const int ln   = lane & 15, quad = lane >> 4;
  const int bh = blockIdx.x >> 4;
  const int qc = blockIdx.x & 15;
  const int h = bh & 7, b = bh >> 3;
  const int len = len_g[b];
  if (qc * 64 >= len) return;
  const int q0 = qc * 64 + wave * 16;

  const u16* Qb = qkv + ((size_t)b * 1024 + q0 + ln) * QKV_LD + h * 64;
  const v8bf aq0 = *(const v8bf*)(Qb + quad * 8);
  const v8bf aq1 = *(const v8bf*)(Qb + 32 + quad * 8);

  const u16* Kbase = qkv + (size_t)b * 1024 * QKV_LD + 512 + h * 64;
  const u16* Vbase = VT + (size_t)bh * 64 * 1024;

  const int r0 = t >> 3,         c0 = (t & 7) * 8;
  const int r1 = (t + 256) >> 3, c1 = c0;
  const u16* Kst0 = Kbase + (size_t)r0 * QKV_LD + c0;
  const u16* Kst1 = Kbase + (size_t)r1 * QKV_LD + c1;
  const u16* Vst0 = Vbase + (size_t)r0 * 1024 + c0;
  const u16* Vst1 = Vbase + (size_t)r1 * 1024 + c1;
  u16* KsD0 = &Ks[r0 * 72 + c0]; u16* KsD1 = &Ks[r1 * 72 + c1];
  u16* VsD0 = &Vs[r0 * 72 + c0]; u16* VsD1 = &Vs[r1 * 72 + c1];

  float m_i[4], l_i[4];
  #pragma unroll
  for (int r = 0; r < 4; ++r){ m_i[r] = -1e30f; l_i[r] = 0.f; }
  v4f o_acc[4];
  #pragma unroll
  for (int c = 0; c < 4; ++c) o_acc[c] = (v4f){0.f,0.f,0.f,0.f};

  u16* P = Pl[wave];

  v8u ck0 = *(const v8u*)Kst0;
  v8u ck1 = *(const v8u*)Kst1;
  v8u cv0 = *(const v8u*)Vst0;
  v8u cv1 = *(const v8u*)Vst1;

  for (int j0 = 0; j0 < len; j0 += 64){
    __syncthreads();
    *(v8u*)KsD0 = ck0; *(v8u*)KsD1 = ck1;
    *(v8u*)VsD0 = cv0; *(v8u*)VsD1 = cv1;
    __syncthreads();

    const int jn = j0 + 64;
    if (jn < len){
      ck0 = *(const v8u*)(Kst0 + (size_t)jn * QKV_LD);
      ck1 = *(const v8u*)(Kst1 + (size_t)jn * QKV_LD);
      cv0 = *(const v8u*)(Vst0 + jn);
      cv1 = *(const v8u*)(Vst1 + jn);
    }

    const bool tail = (len - j0) < 64;

    v4f s[4];
    #pragma unroll
    for (int st = 0; st < 4; ++st){
      const u16* kr = &Ks[(st * 16 + ln) * 72];
      v4f ss = {0.f,0.f,0.f,0.f};
      ss = __builtin_amdgcn_mfma_f32_16x16x32_bf16(aq0, *(const v8bf*)(kr + quad * 8),      ss, 0,0,0);
      ss = __builtin_amdgcn_mfma_f32_16x16x32_bf16(aq1, *(const v8bf*)(kr + 32 + quad * 8), ss, 0,0,0);
      s[st] = ss;
    }

    float p[4][4], mt[4];
    #pragma unroll
    for (int r = 0; r < 4; ++r) mt[r] = -1e30f;
    #pragma unroll
    for (int st = 0; st < 4; ++st){
      const bool dead = tail && (j0 + st * 16 + ln) >= len;
      #pragma unroll
      for (int r = 0; r < 4; ++r){
        float sc = dead ? -1e30f : s[st][r] * 0.125f;
        p[st][r] = sc;
        mt[r] = fmaxf(mt[r], sc);
      }
    }
    #pragma unroll
    for (int off = 1; off < 16; off <<= 1)
      #pragma unroll
      for (int r = 0; r < 4; ++r) mt[r] = fmaxf(mt[r], __shfl_xor(mt[r], off));

    float alpha[4], ts[4];
    #pragma unroll
    for (int r = 0; r < 4; ++r){
      const float mn = fmaxf(m_i[r], mt[r]);
      alpha[r] = __expf(m_i[r] - mn);
      m_i[r] = mn;
    }
    #pragma unroll
    for (int st = 0; st < 4; ++st)
      #pragma unroll
      for (int r = 0; r < 4; ++r) p[st][r] = __expf(p[st][r] - m_i[r]);
    #pragma unroll
    for (int r = 0; r < 4; ++r) ts[r] = (p[0][r] + p[1][r]) + (p[2][r] + p[3][r]);
    #pragma unroll
    for (int off = 1; off < 16; off <<= 1)
      #pragma unroll
      for (int r = 0; r < 4; ++r) ts[r] += __shfl_xor(ts[r], off);
    #pragma unroll
    for (int r = 0; r < 4; ++r) l_i[r] = l_i[r] * alpha[r] + ts[r];
    #pragma unroll
    for (int c = 0; c < 4; ++c)
      #pragma unroll
      for (int r = 0; r < 4; ++r) o_acc[c][r] *= alpha[r];

    #pragma unroll
    for (int st = 0; st < 4; ++st)
      #pragma unroll
      for (int r = 0; r < 4; ++r)
        P[(quad * 4 + r) * 72 + st * 16 + ln] = f2b(p[st][r]);
    const v8bf ap0 = *(const v8bf*)&P[ln * 72 + quad * 8];
    const v8bf ap1 = *(const v8bf*)&P[ln * 72 + 32 + quad * 8];

    #pragma unroll
    for (int c = 0; c < 4; ++c){
      const u16* vr = &Vs[(c * 16 + ln) * 72];
      o_acc[c] = __builtin_amdgcn_mfma_f32_16x16x32_bf16(ap0, *(const v8bf*)(vr + quad * 8),      o_acc[c], 0,0,0);
      o_acc[c] = __builtin_amdgcn_mfma_f32_16x16x32_bf16(ap1, *(const v8bf*)(vr + 32 + quad * 8), o_acc[c], 0,0,0);
    }
  }

  u16* Ob = O + ((size_t)b * 1024 + q0) * 512 + h * 64;
  #pragma unroll
  for (int c = 0; c < 4; ++c)
    #pragma unroll
    for (int r = 0; r < 4; ++r)
      Ob[(size_t)(quad * 4 + r) * 512 + c * 16 + ln] = f2b(o_acc[c][r] / l_i[r]);
}

// ---------------------------------------------------------------------------
// Fused residual + query-mask + LayerNorm: X = LN(Y*qm + X) * g + b
// OUT=1: final layer -> write f32 to fout instead of xb.
// ---------------------------------------------------------------------------
template<int OUT>
__global__ __launch_bounds__(256) void ln_res(
    const u16* __restrict__ Y, const u16* __restrict__ qm,
    const u16* __restrict__ g, const u16* __restrict__ beta,
    u16* __restrict__ X, float* __restrict__ fout)
{
  const int lane = threadIdx.x & 63;
  const int wave = threadIdx.x >> 6;
  const int row  = blockIdx.x * 4 + wave;

  const float qv = b2f(qm[row]);
  const u16* y = Y + (size_t)row * ND;
  u16*       x = X + (size_t)row * ND;

  v8u yv = *(const v8u*)(y + lane * 8);
  v8u xv = *(const v8u*)(x + lane * 8);
  float tt[8]; float s = 0.f, s2 = 0.f;
  #pragma unroll
  for (int i = 0; i < 8; ++i){
    tt[i] = b2f(yv[i]) * qv + b2f(xv[i]);
    s  += tt[i];
    s2 += tt[i] * tt[i];
  }
  #pragma unroll
  for (int off = 1; off < 64; off <<= 1){
    s  += __shfl_xor(s,  off);
    s2 += __shfl_xor(s2, off);
  }
  const float mean = s * (1.f / ND);
  const float var  = fmaxf(s2 * (1.f / ND) - mean * mean, 0.f);
  const float inv  = rsqrtf(var + LN_EPS);

  v8u gv = *(const v8u*)(g    + lane * 8);
  v8u bv = *(const v8u*)(beta + lane * 8);
  float ov[8];
  #pragma unroll
  for (int i = 0; i < 8; ++i)
    ov[i] = (tt[i] - mean) * inv * b2f(gv[i]) + b2f(bv[i]);

  if (OUT){
    float4 o0, o1;
    o0.x=ov[0]; o0.y=ov[1]; o0.z=ov[2]; o0.w=ov[3];
    o1.x=ov[4]; o1.y=ov[5]; o1.z=ov[6]; o1.w=ov[7];
    float* fo = fout + (size_t)row * ND + lane * 8;
    *(float4*)fo = o0;
    *(float4*)(fo + 4) = o1;
  } else {
    v8u o;
    #pragma unroll
    for (int i = 0; i < 8; ++i) o[i] = f2b(ov[i]);
    *(v8u*)(x + lane * 8) = o;
  }
}

// ---------------------------------------------------------------------------
extern "C" void kernel_launch(void* const* d_in, const int* in_sizes, int n_in,
                              void* d_out, int out_size, void* d_ws, size_t ws_size,
                              hipStream_t stream)
{
  char* ws = (char*)d_ws;
  const size_t MiB = 1u << 20;
  u16* qkv = (u16*)(ws);               // 12 MiB
  u16* VT  = (u16*)(ws + 12 * MiB);    // 4 MiB
  u16* hb  = (u16*)(ws);               // FFN hidden reuses [0,16M)
  u16* tb1 = (u16*)(ws);
  u16* xb   = (u16*)(ws + 16 * MiB);
  u16* kcan = (u16*)(ws + 20 * MiB);
  u16* ob   = (u16*)(ws + 24 * MiB);
  u16* tb2  = ob;
  u16* wcan = (u16*)(ws + 28 * MiB);
  int* len  = (int*)(ws + 65 * MiB);

  const float* f_qm = (const float*)d_in[2];

  conv_qk<<<2048, 256, 0, stream>>>((const float*)d_in[0], (const float*)d_in[1], xb, kcan);
  conv_qkvw<<<2304, 256, 0, stream>>>((const float*)d_in[4], (const float*)d_in[6],
                                      (const float*)d_in[8], wcan);
  conv_w3<<<6912, 256, 0, stream>>>((const float*)d_in[10], (const float*)d_in[12],
                                    (const float*)d_in[14], wcan);
  conv_small<<<22, 256, 0, stream>>>(
      (const float*)d_in[5],  (const float*)d_in[7],  (const float*)d_in[9],
      (const float*)d_in[11], (const float*)d_in[13], (const float*)d_in[15],
      (const float*)d_in[16], (const float*)d_in[17],
      (const float*)d_in[18], (const float*)d_in[19], f_qm, wcan);
  compute_len<<<4, 256, 0, stream>>>(f_qm, len);

  for (int i = 0; i < NLAYERS; ++i){
    const u16* Wqkv_i = wcan + WQKV + (size_t)i * 786432;
    const u16* bqkv_i = wcan + BQKV + (size_t)i * 1536;
    const u16* Wo_i = wcan + WOo + (size_t)i * 262144;
    const u16* W1_i = wcan + W1o + (size_t)i * 1048576;
    const u16* W2_i = wcan + W2o + (size_t)i * 1048576;

    // grids chosen for >=1.5 live blocks/CU after mask-skip (R5 lesson)
    gemm_k<64,128,0,1><<<dim3(12, 64), 256, 0, stream>>>(
        xb, kcan, Wqkv_i, bqkv_i, qkv, VT, len, QKV_LD, ND);

    attn_kernel<<<512, 256, 0, stream>>>(qkv, VT, len, ob);

    gemm_k<64,64,0,0><<<dim3(8, 64), 256, 0, stream>>>(
        ob, ob, Wo_i, wcan + BOo + (size_t)i * ND, tb1, nullptr, len, ND, ND);
    ln_res<0><<<NROWS / 4, 256, 0, stream>>>(tb1, wcan + QMo,
        wcan + L1G + (size_t)i * ND, wcan + L1B + (size_t)i * ND, xb, nullptr);

    gemm_k<128,128,1,0><<<dim3(16, 32), 256, 0, stream>>>(
        xb, xb, W1_i, wcan + B1o + (size_t)i * NF, hb, nullptr, len, NF, ND);
    gemm_k<64,64,0,0><<<dim3(8, 64), 256, 0, stream>>>(
        hb, hb, W2_i, wcan + B2o + (size_t)i * ND, tb2, nullptr, len, ND, NF);

    if (i < NLAYERS - 1)
      ln_res<0><<<NROWS / 4, 256, 0, stream>>>(tb2, wcan + QMo,
          wcan + L2G + (size_t)i * ND, wcan + L2B + (size_t)i * ND, xb, nullptr);
    else
      ln_res<1><<<NROWS / 4, 256, 0, stream>>>(tb2, wcan + QMo,
          wcan + L2G + (size_t)i * ND, wcan + L2B + (size_t)i * ND, xb, (float*)d_out);
  }
}